// Round 5
// baseline (3454.364 us; speedup 1.0000x reference)
//
#include <hip/hip_runtime.h>
#include <math.h>

#define T_DIM 512
#define B_DIM 256
#define D_DIM 256
#define H_DIM 256
#define G_DIM 1024   // 4*H
#define K_DIM 512    // D + H
#define NROUNDS 40
#define TILE_ROWS 32
#define K0_TAIL 8

typedef __attribute__((ext_vector_type(8))) short short8;
typedef __attribute__((ext_vector_type(4))) float f32x4;

__device__ __forceinline__ unsigned int f2bf(float f) {
    unsigned int b = __float_as_uint(f);
    return (b + 0x7FFFu + ((b >> 16) & 1u)) >> 16;   // round-to-nearest-even bf16
}
__device__ __forceinline__ unsigned long long pack4(float4 v) {
    const unsigned int lo = (f2bf(v.y) << 16) | f2bf(v.x);
    const unsigned int hi = (f2bf(v.w) << 16) | f2bf(v.z);
    return ((unsigned long long)hi << 32) | lo;
}
__device__ __forceinline__ float sigm(float x) { return 1.0f / (1.0f + __expf(-x)); }
__device__ __forceinline__ float tanh_fast(float x) { return 2.0f / (1.0f + __expf(-2.0f * x)) - 1.0f; }

// Prepack W into MFMA B-fragment order, bf16.
__global__ __launch_bounds__(256) void k_prep_weights(
    const float* __restrict__ W_ih, const float* __restrict__ W_hh,
    const float* __restrict__ b_ih, const float* __restrict__ b_hh,
    unsigned int* __restrict__ Wb, float* __restrict__ bias)
{
    const int idx = blockIdx.x * 256 + threadIdx.x;   // 0 .. 262143
    const int jp = idx & 3, l = (idx >> 2) & 63, ks = (idx >> 8) & 15, nt = idx >> 12;
    const int g = nt * 16 + (l & 15);
    const int k0 = ks * 32 + ((l >> 4) << 3) + 2 * jp;
    const float w0 = (k0 < D_DIM) ? W_ih[g * D_DIM + k0] : W_hh[g * H_DIM + (k0 - D_DIM)];
    const float w1 = (k0 + 1 < D_DIM) ? W_ih[g * D_DIM + k0 + 1] : W_hh[g * H_DIM + (k0 + 1 - D_DIM)];
    Wb[idx] = (f2bf(w1) << 16) | f2bf(w0);
    if (idx < G_DIM) bias[idx] = b_ih[idx] + b_hh[idx];
}

// Parallel kmap + histogram. Block = one t-row; backward scan ~2 coalesced steps expected.
__global__ __launch_bounds__(256) void k_kmap(
    const int* __restrict__ done, int* __restrict__ kmap, int* __restrict__ counts)
{
    __shared__ int lcnt[NROUNDS];
    const int tid = threadIdx.x;
    if (tid < NROUNDS) lcnt[tid] = 0;
    __syncthreads();
    const int t = blockIdx.x, b = tid;
    int kv = t;
    for (int tt = t; tt >= 0; --tt) {
        if (done[tt * B_DIM + b]) { kv = t - tt; break; }
    }
    if (kv > NROUNDS - 1) kv = NROUNDS - 1;
    kmap[t * B_DIM + b] = kv;
    atomicAdd(&lcnt[kv], 1);
    __syncthreads();
    if (tid < NROUNDS && lcnt[tid] > 0) atomicAdd(&counts[tid], lcnt[tid]);
}

__global__ __launch_bounds__(64) void k_offs(
    const int* __restrict__ counts, int* __restrict__ offs, int* __restrict__ cursor)
{
    if (threadIdx.x == 0) {
        int s = 0;
        for (int i = 0; i < NROUNDS; ++i) { offs[i] = s; s += counts[i]; }
    }
    if (threadIdx.x < NROUNDS) cursor[threadIdx.x] = 0;
}

// Two-level scatter: LDS local ranks + one global atomicAdd per (block, bin).
__global__ __launch_bounds__(256) void k_scatter(
    const int* __restrict__ kmap, const int* __restrict__ offs,
    int* __restrict__ cursor, int* __restrict__ rowlist)
{
    __shared__ int lcnt[NROUNDS];
    __shared__ int gbase[NROUNDS];
    const int tid = threadIdx.x;
    if (tid < NROUNDS) lcnt[tid] = 0;
    __syncthreads();
    const int pos = blockIdx.x * 256 + tid;
    const int kv = kmap[pos];
    const int lrank = atomicAdd(&lcnt[kv], 1);
    __syncthreads();
    if (tid < NROUNDS && lcnt[tid] > 0) gbase[tid] = atomicAdd(&cursor[tid], lcnt[tid]);
    __syncthreads();
    rowlist[offs[kv] + gbase[kv] + lrank] = pos;
}

// ---- phase 1: load row list (caller barriers after) ----
__device__ __forceinline__ void tile_posr(
    const int* __restrict__ rowlist, int* posr, int nk, int base, int row0, int tid)
{
    if (tid < TILE_ROWS)
        posr[tid] = (row0 + tid < nk) ? rowlist[base + row0 + tid] : -1;
}

// ---- phase 2: stage A tile (float4 loads, f32->bf16, fragment order) ----
// A_lds fragment layout: short slot ((ks*2+mb)*64 + l)*8 + j <-> row mb*16+(l&15), k = ks*32+((l>>4)<<3)+j
__device__ __forceinline__ void tile_stage(
    const float* __restrict__ x, const float* __restrict__ h0,
    const int* __restrict__ done, const float* __restrict__ out,
    short* A_lds, const int* posr, int kk, int tid)
{
    unsigned long long* A_u64 = (unsigned long long*)A_lds;
    #pragma unroll 4
    for (int it = 0; it < 16; ++it) {
        const int q = it * 256 + tid;             // u64 slot, 0..4095
        const int ks = q >> 8, mb = (q >> 7) & 1, sl = (q >> 1) & 63, jq = q & 1;
        const int r = mb * 16 + (sl & 15);
        const int c = ks * 32 + ((sl >> 4) << 3) + 4 * jq;
        const int pos = posr[r];
        float4 v = {0.f, 0.f, 0.f, 0.f};
        if (pos >= 0) {
            if (c < D_DIM) {
                v = *(const float4*)(x + (size_t)pos * D_DIM + c);
            } else {
                const int u = c - D_DIM;
                if (kk > 0)          v = *(const float4*)(out + (size_t)(pos - B_DIM) * H_DIM + u);
                else if (!done[pos]) v = *(const float4*)(h0 + (size_t)(pos & (B_DIM - 1)) * H_DIM + u);
            }
        }
        A_u64[q] = pack4(v);
    }
}

// ---- phase 3: MFMA + fused LSTM pointwise ----
__device__ __forceinline__ void tile_compute(
    const float* __restrict__ c0, const int* __restrict__ done,
    const short* __restrict__ Wb,
    float* __restrict__ out, float* __restrict__ c_buf,
    const short* A_lds, const int* posr, int nk, int kk, int row0, int tid,
    const float* bI, const float* bF, const float* bG, const float* bO)
{
    const int w = tid >> 6, l = tid & 63;
    const int lr = l >> 4, lc = l & 15;

    f32x4 acc[4][2][4];
    #pragma unroll
    for (int gt = 0; gt < 4; ++gt)
        #pragma unroll
        for (int mb = 0; mb < 2; ++mb)
            #pragma unroll
            for (int uq = 0; uq < 4; ++uq)
                acc[gt][mb][uq] = (f32x4){0.f, 0.f, 0.f, 0.f};

    #pragma unroll 1
    for (int ks = 0; ks < 16; ++ks) {
        const short8 a0 = *(const short8*)&A_lds[((ks * 2 + 0) * 64 + l) * 8];
        const short8 a1 = *(const short8*)&A_lds[((ks * 2 + 1) * 64 + l) * 8];
        const short* wb_base = Wb + ((size_t)ks * 64 + l) * 8;
        #pragma unroll
        for (int gt = 0; gt < 4; ++gt) {
            #pragma unroll
            for (int uq = 0; uq < 4; ++uq) {
                const int nt = gt * 16 + w * 4 + uq;
                const short8 b = *(const short8*)(wb_base + (size_t)nt * 16 * 64 * 8);
                acc[gt][0][uq] = __builtin_amdgcn_mfma_f32_16x16x32_bf16(a0, b, acc[gt][0][uq], 0, 0, 0);
                acc[gt][1][uq] = __builtin_amdgcn_mfma_f32_16x16x32_bf16(a1, b, acc[gt][1][uq], 0, 0, 0);
            }
        }
    }

    #pragma unroll
    for (int mb = 0; mb < 2; ++mb) {
        #pragma unroll
        for (int uq = 0; uq < 4; ++uq) {
            const int u = w * 64 + uq * 16 + lc;
            #pragma unroll
            for (int j = 0; j < 4; ++j) {
                const int gr = row0 + mb * 16 + lr * 4 + j;
                if (gr < nk) {
                    const int pos = posr[mb * 16 + lr * 4 + j];
                    float cp = 0.0f;
                    if (kk > 0)           cp = c_buf[(size_t)(pos - B_DIM) * H_DIM + u];
                    else if (!done[pos])  cp = c0[(size_t)(pos & (B_DIM - 1)) * H_DIM + u];
                    const float si = sigm(acc[0][mb][uq][j] + bI[uq]);
                    const float sf = sigm(acc[1][mb][uq][j] + bF[uq]);
                    const float tg = tanh_fast(acc[2][mb][uq][j] + bG[uq]);
                    const float so = sigm(acc[3][mb][uq][j] + bO[uq]);
                    const float cn = sf * cp + si * tg;
                    const float hn = so * tanh_fast(cn);
                    c_buf[(size_t)pos * H_DIM + u] = cn;
                    out[(size_t)pos * H_DIM + u]  = hn;
                }
            }
        }
    }
}

// Rounds 0..K0_TAIL-1: grid-parallel.
__global__ __launch_bounds__(256, 4) void k_round(
    const float* __restrict__ x, const float* __restrict__ h0,
    const float* __restrict__ c0, const int* __restrict__ done,
    const short* __restrict__ Wb, const float* __restrict__ bias,
    const int* __restrict__ counts, const int* __restrict__ offs,
    const int* __restrict__ rowlist,
    float* __restrict__ out, float* __restrict__ c_buf, int kk)
{
    __shared__ short A_lds[16 * 2 * 64 * 8];   // 32 KiB
    __shared__ int posr[TILE_ROWS];
    const int nk = counts[kk];
    const int base = offs[kk];
    const int tid = threadIdx.x;
    const int w = tid >> 6, lc = tid & 15;

    const int u_pw = w * 64 + lc;
    float bI[4], bF[4], bG[4], bO[4];
    #pragma unroll
    for (int uq = 0; uq < 4; ++uq) {
        bI[uq] = bias[u_pw + uq * 16];
        bF[uq] = bias[256 + u_pw + uq * 16];
        bG[uq] = bias[512 + u_pw + uq * 16];
        bO[uq] = bias[768 + u_pw + uq * 16];
    }

    for (int tile = blockIdx.x; tile * TILE_ROWS < nk; tile += gridDim.x) {
        const int row0 = tile * TILE_ROWS;
        tile_posr(rowlist, posr, nk, base, row0, tid);
        __syncthreads();
        tile_stage(x, h0, done, out, A_lds, posr, kk, tid);
        __syncthreads();
        tile_compute(c0, done, Wb, out, c_buf, A_lds, posr, nk, kk, row0, tid, bI, bF, bG, bO);
        __syncthreads();
    }
}

// Tail rounds K0..39 in ONE block (1024 thr = 4 groups x 256, 4 x 32KiB LDS slabs).
// Cross-round RAW is block-local -> __syncthreads (workgroup-scope fence) orders it.
// All barriers executed uniformly; OOB tiles neutralized via posr=-1 / gr<nk guards.
__global__ __launch_bounds__(1024, 4) void k_tail(
    const float* __restrict__ x, const float* __restrict__ h0,
    const float* __restrict__ c0, const int* __restrict__ done,
    const short* __restrict__ Wb, const float* __restrict__ bias,
    const int* __restrict__ counts, const int* __restrict__ offs,
    const int* __restrict__ rowlist,
    float* __restrict__ out, float* __restrict__ c_buf, int k0)
{
    __shared__ short A_lds[4][16 * 2 * 64 * 8];   // 4 x 32 KiB
    __shared__ int posr[4][TILE_ROWS];
    const int grp = threadIdx.x >> 8;
    const int tid = threadIdx.x & 255;
    const int w = tid >> 6, lc = tid & 15;

    const int u_pw = w * 64 + lc;
    float bI[4], bF[4], bG[4], bO[4];
    #pragma unroll
    for (int uq = 0; uq < 4; ++uq) {
        bI[uq] = bias[u_pw + uq * 16];
        bF[uq] = bias[256 + u_pw + uq * 16];
        bG[uq] = bias[512 + u_pw + uq * 16];
        bO[uq] = bias[768 + u_pw + uq * 16];
    }

    for (int kk = k0; kk < NROUNDS; ++kk) {
        const int nk = counts[kk];
        const int base = offs[kk];
        const int ntiles = (nk + TILE_ROWS - 1) / TILE_ROWS;
        const int passes = (ntiles + 3) / 4;
        for (int p = 0; p < passes; ++p) {
            const int tile = p * 4 + grp;            // may be >= ntiles: harmless
            const int row0 = tile * TILE_ROWS;
            tile_posr(rowlist, posr[grp], nk, base, row0, tid);
            __syncthreads();
            tile_stage(x, h0, done, out, A_lds[grp], posr[grp], kk, tid);
            __syncthreads();
            tile_compute(c0, done, Wb, out, c_buf, A_lds[grp], posr[grp],
                         nk, kk, row0, tid, bI, bF, bG, bO);
            __syncthreads();   // round/tile results visible before next staging
        }
    }
}

// hT = out rows at t=511 ; cT = c_buf at t=511
__global__ __launch_bounds__(256) void k_final(const float* __restrict__ c_buf, float* __restrict__ out)
{
    const size_t i = (size_t)blockIdx.x * 256 + threadIdx.x;
    const size_t featN = (size_t)T_DIM * B_DIM * H_DIM;
    const size_t last  = (size_t)(T_DIM - 1) * B_DIM * H_DIM;
    out[featN + i] = out[last + i];
    out[featN + (size_t)B_DIM * H_DIM + i] = c_buf[last + i];
}

__global__ __launch_bounds__(64) void k_zero(int* __restrict__ counts)
{
    if (threadIdx.x < NROUNDS) counts[threadIdx.x] = 0;
}

extern "C" void kernel_launch(void* const* d_in, const int* in_sizes, int n_in,
                              void* d_out, int out_size, void* d_ws, size_t ws_size,
                              hipStream_t stream)
{
    const float* x    = (const float*)d_in[0];
    const float* h0   = (const float*)d_in[1];
    const float* c0   = (const float*)d_in[2];
    const float* W_ih = (const float*)d_in[3];
    const float* W_hh = (const float*)d_in[4];
    const float* b_ih = (const float*)d_in[5];
    const float* b_hh = (const float*)d_in[6];
    const int*   done = (const int*)d_in[7];
    float* out = (float*)d_out;

    char* ws = (char*)d_ws;
    size_t off = 0;
    float* c_buf = (float*)(ws + off);            off += (size_t)T_DIM * B_DIM * H_DIM * 4;  // 128 MiB
    unsigned int* Wb = (unsigned int*)(ws + off); off += (size_t)(K_DIM / 2) * G_DIM * 4;    // 1 MiB
    float* bias = (float*)(ws + off);             off += (size_t)G_DIM * 4;
    int* kmap    = (int*)(ws + off);              off += (size_t)T_DIM * B_DIM * 4;
    int* rowlist = (int*)(ws + off);              off += (size_t)T_DIM * B_DIM * 4;
    int* counts  = (int*)(ws + off);              off += 256;
    int* offs    = (int*)(ws + off);              off += 256;
    int* cursor  = (int*)(ws + off);              off += 256;

    k_zero<<<1, 64, 0, stream>>>(counts);
    k_prep_weights<<<1024, 256, 0, stream>>>(W_ih, W_hh, b_ih, b_hh, Wb, bias);
    k_kmap<<<T_DIM, 256, 0, stream>>>(done, kmap, counts);
    k_offs<<<1, 64, 0, stream>>>(counts, offs, cursor);
    k_scatter<<<T_DIM * B_DIM / 256, 256, 0, stream>>>(kmap, offs, cursor, rowlist);

    int est = 70000;   // statistical upper bound on round-0 rows; ~halves each round
    for (int k = 0; k < K0_TAIL; ++k) {
        int grid = est / TILE_ROWS + 8;
        if (grid > 2048) grid = 2048;
        if (grid < 8) grid = 8;
        k_round<<<grid, 256, 0, stream>>>(x, h0, c0, done, (const short*)Wb, bias,
                                          counts, offs, rowlist, out, c_buf, k);
        est >>= 1;
    }
    k_tail<<<1, 1024, 0, stream>>>(x, h0, c0, done, (const short*)Wb, bias,
                                   counts, offs, rowlist, out, c_buf, K0_TAIL);
    k_final<<<B_DIM * H_DIM / 256, 256, 0, stream>>>(c_buf, out);
}

// Round 6
// 889.385 us; speedup vs baseline: 3.8840x; 3.8840x over previous
//
#include <hip/hip_runtime.h>
#include <math.h>

#define T_DIM 512
#define B_DIM 256
#define D_DIM 256
#define H_DIM 256
#define G_DIM 1024   // 4*H
#define K_DIM 512    // D + H
#define NROUNDS 40
#define TILE_ROWS 32
#define CHAIN_K 8    // rounds 0..7 batched; steps >=8 via per-segment finisher

typedef __attribute__((ext_vector_type(8))) short short8;
typedef __attribute__((ext_vector_type(4))) float f32x4;

__device__ __forceinline__ unsigned int f2bf(float f) {
    unsigned int b = __float_as_uint(f);
    return (b + 0x7FFFu + ((b >> 16) & 1u)) >> 16;   // round-to-nearest-even bf16
}
__device__ __forceinline__ unsigned long long pack4(float4 v) {
    const unsigned int lo = (f2bf(v.y) << 16) | f2bf(v.x);
    const unsigned int hi = (f2bf(v.w) << 16) | f2bf(v.z);
    return ((unsigned long long)hi << 32) | lo;
}
__device__ __forceinline__ float sigm(float x) { return 1.0f / (1.0f + __expf(-x)); }
__device__ __forceinline__ float tanh_fast(float x) { return 2.0f / (1.0f + __expf(-2.0f * x)) - 1.0f; }

// Prepack W into MFMA B-fragment order, bf16 (for k_round).
__global__ __launch_bounds__(256) void k_prep_weights(
    const float* __restrict__ W_ih, const float* __restrict__ W_hh,
    const float* __restrict__ b_ih, const float* __restrict__ b_hh,
    unsigned int* __restrict__ Wb, float* __restrict__ bias)
{
    const int idx = blockIdx.x * 256 + threadIdx.x;   // 0 .. 262143
    const int jp = idx & 3, l = (idx >> 2) & 63, ks = (idx >> 8) & 15, nt = idx >> 12;
    const int g = nt * 16 + (l & 15);
    const int k0 = ks * 32 + ((l >> 4) << 3) + 2 * jp;
    const float w0 = (k0 < D_DIM) ? W_ih[g * D_DIM + k0] : W_hh[g * H_DIM + (k0 - D_DIM)];
    const float w1 = (k0 + 1 < D_DIM) ? W_ih[g * D_DIM + k0 + 1] : W_hh[g * H_DIM + (k0 + 1 - D_DIM)];
    Wb[idx] = (f2bf(w1) << 16) | f2bf(w0);
    if (idx < G_DIM) bias[idx] = b_ih[idx] + b_hh[idx];
}

// Prepack W k-major for the finisher GEMV: Wq[kq*1024+g] = bf16x4 of W[4kq..4kq+3][g].
__global__ __launch_bounds__(256) void k_prep_wq(
    const float* __restrict__ W_ih, const float* __restrict__ W_hh,
    unsigned long long* __restrict__ Wq)
{
    const int idx = blockIdx.x * 256 + threadIdx.x;   // 0..131071
    const int kq = idx >> 10, g = idx & (G_DIM - 1);
    float w[4];
    #pragma unroll
    for (int j = 0; j < 4; ++j) {
        const int k = kq * 4 + j;
        w[j] = (k < D_DIM) ? W_ih[g * D_DIM + k] : W_hh[g * H_DIM + (k - D_DIM)];
    }
    Wq[idx] = pack4((float4){w[0], w[1], w[2], w[3]});
}

// Parallel kmap + histogram. kmap stores TRUE steps-since-reset (unclamped);
// histogram bins clamp at NROUNDS-1.
__global__ __launch_bounds__(256) void k_kmap(
    const int* __restrict__ done, int* __restrict__ kmap, int* __restrict__ counts)
{
    __shared__ int lcnt[NROUNDS];
    const int tid = threadIdx.x;
    if (tid < NROUNDS) lcnt[tid] = 0;
    __syncthreads();
    const int t = blockIdx.x, b = tid;
    int kv = t;
    for (int tt = t; tt >= 0; --tt) {
        if (done[tt * B_DIM + b]) { kv = t - tt; break; }
    }
    kmap[t * B_DIM + b] = kv;
    const int bin = kv < NROUNDS ? kv : NROUNDS - 1;
    atomicAdd(&lcnt[bin], 1);
    __syncthreads();
    if (tid < NROUNDS && lcnt[tid] > 0) atomicAdd(&counts[tid], lcnt[tid]);
}

__global__ __launch_bounds__(64) void k_offs(
    const int* __restrict__ counts, int* __restrict__ offs, int* __restrict__ cursor)
{
    if (threadIdx.x == 0) {
        int s = 0;
        for (int i = 0; i < NROUNDS; ++i) { offs[i] = s; s += counts[i]; }
    }
    if (threadIdx.x < NROUNDS) cursor[threadIdx.x] = 0;
}

// Two-level scatter: LDS local ranks + one global atomicAdd per (block, bin).
__global__ __launch_bounds__(256) void k_scatter(
    const int* __restrict__ kmap, const int* __restrict__ offs,
    int* __restrict__ cursor, int* __restrict__ rowlist)
{
    __shared__ int lcnt[NROUNDS];
    __shared__ int gbase[NROUNDS];
    const int tid = threadIdx.x;
    if (tid < NROUNDS) lcnt[tid] = 0;
    __syncthreads();
    const int pos = blockIdx.x * 256 + tid;
    const int kv0 = kmap[pos];
    const int kv = kv0 < NROUNDS ? kv0 : NROUNDS - 1;
    const int lrank = atomicAdd(&lcnt[kv], 1);
    __syncthreads();
    if (tid < NROUNDS && lcnt[tid] > 0) gbase[tid] = atomicAdd(&cursor[tid], lcnt[tid]);
    __syncthreads();
    rowlist[offs[kv] + gbase[kv] + lrank] = pos;
}

// Rounds 0..CHAIN_K-1: grid-parallel batched MFMA.
// Block: 256 thr (4 waves). Wave w owns hidden units [w*64, w*64+64), all 4 gates.
// A_lds fragment layout: short slot ((ks*2+mb)*64 + l)*8 + j <->
//   row mb*16+(l&15), k = ks*32+((l>>4)<<3)+j
__global__ __launch_bounds__(256, 2) void k_round(
    const float* __restrict__ x, const float* __restrict__ h0,
    const float* __restrict__ c0, const int* __restrict__ done,
    const short* __restrict__ Wb, const float* __restrict__ bias,
    const int* __restrict__ counts, const int* __restrict__ offs,
    const int* __restrict__ rowlist,
    float* __restrict__ out, float* __restrict__ c_buf, int kk)
{
    __shared__ short A_lds[16 * 2 * 64 * 8];   // 32 KiB
    __shared__ int posr[TILE_ROWS];
    const int nk = counts[kk];
    const int base = offs[kk];
    const int tid = threadIdx.x;
    const int w = tid >> 6, l = tid & 63;
    const int lr = l >> 4, lc = l & 15;

    const int u_pw = w * 64 + lc;
    float bI[4], bF[4], bG[4], bO[4];
    #pragma unroll
    for (int uq = 0; uq < 4; ++uq) {
        bI[uq] = bias[u_pw + uq * 16];
        bF[uq] = bias[256 + u_pw + uq * 16];
        bG[uq] = bias[512 + u_pw + uq * 16];
        bO[uq] = bias[768 + u_pw + uq * 16];
    }

    for (int tile = blockIdx.x; tile * TILE_ROWS < nk; tile += gridDim.x) {
        const int row0 = tile * TILE_ROWS;

        if (tid < TILE_ROWS)
            posr[tid] = (row0 + tid < nk) ? rowlist[base + row0 + tid] : -1;
        __syncthreads();

        // stage A: float4 loads, f32->bf16, fragment order
        unsigned long long* A_u64 = (unsigned long long*)A_lds;
        #pragma unroll 4
        for (int it = 0; it < 16; ++it) {
            const int q = it * 256 + tid;             // u64 slot, 0..4095
            const int ks = q >> 8, mb = (q >> 7) & 1, sl = (q >> 1) & 63, jq = q & 1;
            const int r = mb * 16 + (sl & 15);
            const int c = ks * 32 + ((sl >> 4) << 3) + 4 * jq;
            const int pos = posr[r];
            float4 v = {0.f, 0.f, 0.f, 0.f};
            if (pos >= 0) {
                if (c < D_DIM) {
                    v = *(const float4*)(x + (size_t)pos * D_DIM + c);
                } else {
                    const int u = c - D_DIM;
                    if (kk > 0)          v = *(const float4*)(out + (size_t)(pos - B_DIM) * H_DIM + u);
                    else if (!done[pos]) v = *(const float4*)(h0 + (size_t)(pos & (B_DIM - 1)) * H_DIM + u);
                }
            }
            A_u64[q] = pack4(v);
        }
        __syncthreads();

        f32x4 acc[4][2][4];
        #pragma unroll
        for (int gt = 0; gt < 4; ++gt)
            #pragma unroll
            for (int mb = 0; mb < 2; ++mb)
                #pragma unroll
                for (int uq = 0; uq < 4; ++uq)
                    acc[gt][mb][uq] = (f32x4){0.f, 0.f, 0.f, 0.f};

        #pragma unroll 1
        for (int ks = 0; ks < 16; ++ks) {
            const short8 a0 = *(const short8*)&A_lds[((ks * 2 + 0) * 64 + l) * 8];
            const short8 a1 = *(const short8*)&A_lds[((ks * 2 + 1) * 64 + l) * 8];
            const short* wb_base = Wb + ((size_t)ks * 64 + l) * 8;
            #pragma unroll
            for (int gt = 0; gt < 4; ++gt) {
                #pragma unroll
                for (int uq = 0; uq < 4; ++uq) {
                    const int nt = gt * 16 + w * 4 + uq;
                    const short8 b = *(const short8*)(wb_base + (size_t)nt * 16 * 64 * 8);
                    acc[gt][0][uq] = __builtin_amdgcn_mfma_f32_16x16x32_bf16(a0, b, acc[gt][0][uq], 0, 0, 0);
                    acc[gt][1][uq] = __builtin_amdgcn_mfma_f32_16x16x32_bf16(a1, b, acc[gt][1][uq], 0, 0, 0);
                }
            }
        }

        #pragma unroll
        for (int mb = 0; mb < 2; ++mb) {
            #pragma unroll
            for (int uq = 0; uq < 4; ++uq) {
                const int u = w * 64 + uq * 16 + lc;
                #pragma unroll
                for (int j = 0; j < 4; ++j) {
                    const int gr = row0 + mb * 16 + lr * 4 + j;
                    if (gr < nk) {
                        const int pos = posr[mb * 16 + lr * 4 + j];
                        float cp = 0.0f;
                        if (kk > 0)           cp = c_buf[(size_t)(pos - B_DIM) * H_DIM + u];
                        else if (!done[pos])  cp = c0[(size_t)(pos & (B_DIM - 1)) * H_DIM + u];
                        const float si = sigm(acc[0][mb][uq][j] + bI[uq]);
                        const float sf = sigm(acc[1][mb][uq][j] + bF[uq]);
                        const float tg = tanh_fast(acc[2][mb][uq][j] + bG[uq]);
                        const float so = sigm(acc[3][mb][uq][j] + bO[uq]);
                        const float cn = sf * cp + si * tg;
                        const float hn = so * tanh_fast(cn);
                        c_buf[(size_t)pos * H_DIM + u] = cn;
                        out[(size_t)pos * H_DIM + u]  = hn;
                    }
                }
            }
        }
        __syncthreads();
    }
}

// Per-segment sequential finisher for steps >= CHAIN_K.
// Chain m starts at marker rowlist[offs[8]+m] (kmap==8 exactly); chains are
// independent -> fully parallel across blocks. Thread = gate g (1024 thr).
// Per step: GEMV [1x512]x[512x1024] from k-major bf16 Wq (coalesced 8B/lane),
// h carried in LDS, c in registers (threads 0..255).
__global__ __launch_bounds__(1024) void k_finish(
    const float* __restrict__ x, const unsigned long long* __restrict__ Wq,
    const float* __restrict__ bias,
    const int* __restrict__ counts, const int* __restrict__ offs,
    const int* __restrict__ rowlist, const int* __restrict__ kmap,
    float* __restrict__ out, float* __restrict__ c_buf)
{
    __shared__ float abuf[K_DIM];    // [0,256)=x_t, [256,512)=h_{t-1}
    __shared__ float dots[G_DIM];
    const int g = threadIdx.x;
    const int nch = counts[CHAIN_K];

    for (int m = blockIdx.x; m < nch; m += gridDim.x) {
        const int pos0 = rowlist[offs[CHAIN_K] + m];   // kmap[pos0] == CHAIN_K, t >= 8
        float c_u = 0.0f;
        if (g < H_DIM) {
            abuf[H_DIM + g] = out[(size_t)(pos0 - B_DIM) * H_DIM + g];   // h at t-1
            c_u = c_buf[(size_t)(pos0 - B_DIM) * H_DIM + g];
        }
        int pos = pos0, step = CHAIN_K;
        while (true) {
            if (g < H_DIM) abuf[g] = x[(size_t)pos * D_DIM + g];
            __syncthreads();
            float dot = bias[g];
            #pragma unroll 8
            for (int kq = 0; kq < K_DIM / 4; ++kq) {
                const unsigned long long wq = Wq[(size_t)kq * G_DIM + g];
                const float4 a = *(const float4*)&abuf[kq * 4];
                const unsigned int wlo = (unsigned int)wq;
                const unsigned int whi = (unsigned int)(wq >> 32);
                const float w0 = __uint_as_float(wlo << 16);
                const float w1 = __uint_as_float(wlo & 0xFFFF0000u);
                const float w2 = __uint_as_float(whi << 16);
                const float w3 = __uint_as_float(whi & 0xFFFF0000u);
                dot = fmaf(a.x, w0, dot);
                dot = fmaf(a.y, w1, dot);
                dot = fmaf(a.z, w2, dot);
                dot = fmaf(a.w, w3, dot);
            }
            dots[g] = dot;
            __syncthreads();
            if (g < H_DIM) {
                const float si = sigm(dots[g]);
                const float sf = sigm(dots[H_DIM + g]);
                const float tg = tanh_fast(dots[2 * H_DIM + g]);
                const float so = sigm(dots[3 * H_DIM + g]);
                c_u = sf * c_u + si * tg;
                const float hn = so * tanh_fast(c_u);
                out[(size_t)pos * H_DIM + g]   = hn;
                c_buf[(size_t)pos * H_DIM + g] = c_u;
                abuf[H_DIM + g] = hn;            // h for next step
            }
            pos += B_DIM;
            ++step;
            __syncthreads();                      // h visible; abuf safe to overwrite
            if (pos >= T_DIM * B_DIM) break;
            if (kmap[pos] != step) break;         // segment ended (reset)
        }
        __syncthreads();                          // abuf reuse across chains
    }
}

// hT = out rows at t=511 ; cT = c_buf at t=511
__global__ __launch_bounds__(256) void k_final(const float* __restrict__ c_buf, float* __restrict__ out)
{
    const size_t i = (size_t)blockIdx.x * 256 + threadIdx.x;
    const size_t featN = (size_t)T_DIM * B_DIM * H_DIM;
    const size_t last  = (size_t)(T_DIM - 1) * B_DIM * H_DIM;
    out[featN + i] = out[last + i];
    out[featN + (size_t)B_DIM * H_DIM + i] = c_buf[last + i];
}

__global__ __launch_bounds__(64) void k_zero(int* __restrict__ counts)
{
    if (threadIdx.x < NROUNDS) counts[threadIdx.x] = 0;
}

extern "C" void kernel_launch(void* const* d_in, const int* in_sizes, int n_in,
                              void* d_out, int out_size, void* d_ws, size_t ws_size,
                              hipStream_t stream)
{
    const float* x    = (const float*)d_in[0];
    const float* h0   = (const float*)d_in[1];
    const float* c0   = (const float*)d_in[2];
    const float* W_ih = (const float*)d_in[3];
    const float* W_hh = (const float*)d_in[4];
    const float* b_ih = (const float*)d_in[5];
    const float* b_hh = (const float*)d_in[6];
    const int*   done = (const int*)d_in[7];
    float* out = (float*)d_out;

    char* ws = (char*)d_ws;
    size_t off = 0;
    float* c_buf = (float*)(ws + off);            off += (size_t)T_DIM * B_DIM * H_DIM * 4;  // 128 MiB
    unsigned int* Wb = (unsigned int*)(ws + off); off += (size_t)(K_DIM / 2) * G_DIM * 4;    // 1 MiB
    unsigned long long* Wq = (unsigned long long*)(ws + off); off += (size_t)(K_DIM / 4) * G_DIM * 8; // 1 MiB
    float* bias = (float*)(ws + off);             off += (size_t)G_DIM * 4;
    int* kmap    = (int*)(ws + off);              off += (size_t)T_DIM * B_DIM * 4;
    int* rowlist = (int*)(ws + off);              off += (size_t)T_DIM * B_DIM * 4;
    int* counts  = (int*)(ws + off);              off += 256;
    int* offs    = (int*)(ws + off);              off += 256;
    int* cursor  = (int*)(ws + off);              off += 256;

    k_zero<<<1, 64, 0, stream>>>(counts);
    k_prep_weights<<<1024, 256, 0, stream>>>(W_ih, W_hh, b_ih, b_hh, Wb, bias);
    k_prep_wq<<<512, 256, 0, stream>>>(W_ih, W_hh, Wq);
    k_kmap<<<T_DIM, 256, 0, stream>>>(done, kmap, counts);
    k_offs<<<1, 64, 0, stream>>>(counts, offs, cursor);
    k_scatter<<<T_DIM * B_DIM / 256, 256, 0, stream>>>(kmap, offs, cursor, rowlist);

    int est = 70000;   // statistical upper bound on round-0 rows; ~halves each round
    for (int k = 0; k < CHAIN_K; ++k) {
        int grid = est / TILE_ROWS + 8;
        if (grid > 2048) grid = 2048;
        if (grid < 8) grid = 8;
        k_round<<<grid, 256, 0, stream>>>(x, h0, c0, done, (const short*)Wb, bias,
                                          counts, offs, rowlist, out, c_buf, k);
        est >>= 1;
    }
    // ~counts[8] (~256) independent chains; 512 blocks grid-stride (extras exit fast)
    k_finish<<<512, 1024, 0, stream>>>(x, Wq, bias, counts, offs, rowlist, kmap, out, c_buf);
    k_final<<<B_DIM * H_DIM / 256, 256, 0, stream>>>(c_buf, out);
}

// Round 7
// 718.010 us; speedup vs baseline: 4.8110x; 1.2387x over previous
//
#include <hip/hip_runtime.h>
#include <math.h>

#define T_DIM 512
#define B_DIM 256
#define D_DIM 256
#define H_DIM 256
#define G_DIM 1024   // 4*H
#define K_DIM 512    // D + H
#define NROUNDS 40
#define TILE_ROWS 64
#define CHAIN_K 8    // rounds 0..7 batched; steps >=8 via per-segment finisher

typedef __attribute__((ext_vector_type(8))) short short8;
typedef __attribute__((ext_vector_type(4))) float f32x4;

__device__ __forceinline__ unsigned int f2bf(float f) {
    unsigned int b = __float_as_uint(f);
    return (b + 0x7FFFu + ((b >> 16) & 1u)) >> 16;   // round-to-nearest-even bf16
}
__device__ __forceinline__ unsigned long long pack4(float4 v) {
    const unsigned int lo = (f2bf(v.y) << 16) | f2bf(v.x);
    const unsigned int hi = (f2bf(v.w) << 16) | f2bf(v.z);
    return ((unsigned long long)hi << 32) | lo;
}
__device__ __forceinline__ float sigm(float x) { return 1.0f / (1.0f + __expf(-x)); }
__device__ __forceinline__ float tanh_fast(float x) { return 2.0f / (1.0f + __expf(-2.0f * x)) - 1.0f; }

// Prepack W into MFMA B-fragment order, bf16 (for k_round).
// short idx ((nt*16+ks)*64+l)*8+j  <->  g = nt*16+(l&15), k = ks*32+((l>>4)<<3)+j
__global__ __launch_bounds__(256) void k_prep_weights(
    const float* __restrict__ W_ih, const float* __restrict__ W_hh,
    const float* __restrict__ b_ih, const float* __restrict__ b_hh,
    unsigned int* __restrict__ Wb, float* __restrict__ bias)
{
    const int idx = blockIdx.x * 256 + threadIdx.x;   // 0 .. 262143
    const int jp = idx & 3, l = (idx >> 2) & 63, ks = (idx >> 8) & 15, nt = idx >> 12;
    const int g = nt * 16 + (l & 15);
    const int k0 = ks * 32 + ((l >> 4) << 3) + 2 * jp;
    const float w0 = (k0 < D_DIM) ? W_ih[g * D_DIM + k0] : W_hh[g * H_DIM + (k0 - D_DIM)];
    const float w1 = (k0 + 1 < D_DIM) ? W_ih[g * D_DIM + k0 + 1] : W_hh[g * H_DIM + (k0 + 1 - D_DIM)];
    Wb[idx] = (f2bf(w1) << 16) | f2bf(w0);
    if (idx < G_DIM) bias[idx] = b_ih[idx] + b_hh[idx];
}

// Prepack W k-major for the finisher GEMV: Wq[kq*1024+g] = bf16x4 of W[4kq..4kq+3][g].
__global__ __launch_bounds__(256) void k_prep_wq(
    const float* __restrict__ W_ih, const float* __restrict__ W_hh,
    unsigned long long* __restrict__ Wq)
{
    const int idx = blockIdx.x * 256 + threadIdx.x;   // 0..131071
    const int kq = idx >> 10, g = idx & (G_DIM - 1);
    float w[4];
    #pragma unroll
    for (int j = 0; j < 4; ++j) {
        const int k = kq * 4 + j;
        w[j] = (k < D_DIM) ? W_ih[g * D_DIM + k] : W_hh[g * H_DIM + (k - D_DIM)];
    }
    Wq[idx] = pack4((float4){w[0], w[1], w[2], w[3]});
}

// Parallel kmap + histogram. kmap stores TRUE steps-since-reset (unclamped);
// histogram bins clamp at NROUNDS-1.
__global__ __launch_bounds__(256) void k_kmap(
    const int* __restrict__ done, int* __restrict__ kmap, int* __restrict__ counts)
{
    __shared__ int lcnt[NROUNDS];
    const int tid = threadIdx.x;
    if (tid < NROUNDS) lcnt[tid] = 0;
    __syncthreads();
    const int t = blockIdx.x, b = tid;
    int kv = t;
    for (int tt = t; tt >= 0; --tt) {
        if (done[tt * B_DIM + b]) { kv = t - tt; break; }
    }
    kmap[t * B_DIM + b] = kv;
    const int bin = kv < NROUNDS ? kv : NROUNDS - 1;
    atomicAdd(&lcnt[bin], 1);
    __syncthreads();
    if (tid < NROUNDS && lcnt[tid] > 0) atomicAdd(&counts[tid], lcnt[tid]);
}

__global__ __launch_bounds__(64) void k_offs(
    const int* __restrict__ counts, int* __restrict__ offs, int* __restrict__ cursor)
{
    if (threadIdx.x == 0) {
        int s = 0;
        for (int i = 0; i < NROUNDS; ++i) { offs[i] = s; s += counts[i]; }
    }
    if (threadIdx.x < NROUNDS) cursor[threadIdx.x] = 0;
}

// Two-level scatter: LDS local ranks + one global atomicAdd per (block, bin).
__global__ __launch_bounds__(256) void k_scatter(
    const int* __restrict__ kmap, const int* __restrict__ offs,
    int* __restrict__ cursor, int* __restrict__ rowlist)
{
    __shared__ int lcnt[NROUNDS];
    __shared__ int gbase[NROUNDS];
    const int tid = threadIdx.x;
    if (tid < NROUNDS) lcnt[tid] = 0;
    __syncthreads();
    const int pos = blockIdx.x * 256 + tid;
    const int kv0 = kmap[pos];
    const int kv = kv0 < NROUNDS ? kv0 : NROUNDS - 1;
    const int lrank = atomicAdd(&lcnt[kv], 1);
    __syncthreads();
    if (tid < NROUNDS && lcnt[tid] > 0) gbase[tid] = atomicAdd(&cursor[tid], lcnt[tid]);
    __syncthreads();
    rowlist[offs[kv] + gbase[kv] + lrank] = pos;
}

// Rounds 0..CHAIN_K-1: grid-parallel batched MFMA.
// Block: 512 thr (8 waves), tile = 64 rows x 1024 gates.
// Wave w owns hidden units [w*32, w*32+32) for ALL 4 gates: nt = gt*16 + w*2 + uq.
// acc[gt 4][mb 4][uq 2] = 128 regs. b-frags ping-pong prefetched (ks+1).
// A_lds fragment layout: short slot ((ks*4+mb)*64 + l)*8 + j  <->
//   row mb*16+(l&15), k = ks*32+((l>>4)<<3)+j
__global__ __launch_bounds__(512, 2) void k_round(
    const float* __restrict__ x, const float* __restrict__ h0,
    const float* __restrict__ c0, const int* __restrict__ done,
    const short* __restrict__ Wb, const float* __restrict__ bias,
    const int* __restrict__ counts, const int* __restrict__ offs,
    const int* __restrict__ rowlist,
    float* __restrict__ out, float* __restrict__ c_buf, int kk)
{
    __shared__ short A_lds[16 * 4 * 64 * 8];   // 64 KiB
    __shared__ int posr[TILE_ROWS];
    const int nk = counts[kk];
    const int base = offs[kk];
    const int tid = threadIdx.x;
    const int w = tid >> 6, l = tid & 63;
    const int lr = l >> 4, lc = l & 15;

    const int u_pw = w * 32 + lc;
    float bI[2], bF[2], bG[2], bO[2];
    #pragma unroll
    for (int uq = 0; uq < 2; ++uq) {
        bI[uq] = bias[u_pw + uq * 16];
        bF[uq] = bias[256 + u_pw + uq * 16];
        bG[uq] = bias[512 + u_pw + uq * 16];
        bO[uq] = bias[768 + u_pw + uq * 16];
    }

#define LOAD_B(dst, ksv)                                                        \
    {                                                                           \
        _Pragma("unroll") for (int gt = 0; gt < 4; ++gt)                        \
        _Pragma("unroll") for (int uq = 0; uq < 2; ++uq) {                      \
            const int nt = gt * 16 + w * 2 + uq;                                \
            dst[gt * 2 + uq] = *(const short8*)(Wb + (((size_t)nt * 16 + (ksv)) * 64 + l) * 8); \
        }                                                                       \
    }

#define MFMA_STEP(barr, ksv)                                                    \
    {                                                                           \
        _Pragma("unroll") for (int mb = 0; mb < 4; ++mb) {                      \
            const short8 a = *(const short8*)&A_lds[(((ksv) * 4 + mb) * 64 + l) * 8]; \
            _Pragma("unroll") for (int gt = 0; gt < 4; ++gt)                    \
            _Pragma("unroll") for (int uq = 0; uq < 2; ++uq)                    \
                acc[gt][mb][uq] = __builtin_amdgcn_mfma_f32_16x16x32_bf16(      \
                    a, barr[gt * 2 + uq], acc[gt][mb][uq], 0, 0, 0);            \
        }                                                                       \
    }

    for (int tile = blockIdx.x; tile * TILE_ROWS < nk; tile += gridDim.x) {
        const int row0 = tile * TILE_ROWS;

        if (tid < TILE_ROWS)
            posr[tid] = (row0 + tid < nk) ? rowlist[base + row0 + tid] : -1;
        __syncthreads();

        // stage A: float4 loads, f32->bf16, fragment order. 8192 u64 slots / 512 thr.
        unsigned long long* A_u64 = (unsigned long long*)A_lds;
        #pragma unroll 4
        for (int it = 0; it < 16; ++it) {
            const int q = it * 512 + tid;             // u64 slot, 0..8191
            const int ks = q >> 9, mb = (q >> 7) & 3, sl = (q >> 1) & 63, jq = q & 1;
            const int r = mb * 16 + (sl & 15);
            const int c = ks * 32 + ((sl >> 4) << 3) + 4 * jq;
            const int pos = posr[r];
            float4 v = {0.f, 0.f, 0.f, 0.f};
            if (pos >= 0) {
                if (c < D_DIM) {
                    v = *(const float4*)(x + (size_t)pos * D_DIM + c);
                } else {
                    const int u = c - D_DIM;
                    if (kk > 0)          v = *(const float4*)(out + (size_t)(pos - B_DIM) * H_DIM + u);
                    else if (!done[pos]) v = *(const float4*)(h0 + (size_t)(pos & (B_DIM - 1)) * H_DIM + u);
                }
            }
            A_u64[q] = pack4(v);
        }
        __syncthreads();

        f32x4 acc[4][4][2];
        #pragma unroll
        for (int gt = 0; gt < 4; ++gt)
            #pragma unroll
            for (int mb = 0; mb < 4; ++mb)
                #pragma unroll
                for (int uq = 0; uq < 2; ++uq)
                    acc[gt][mb][uq] = (f32x4){0.f, 0.f, 0.f, 0.f};

        short8 b0[8], b1[8];
        LOAD_B(b0, 0);
        #pragma unroll 1
        for (int ks = 0; ks < 16; ks += 2) {
            LOAD_B(b1, ks + 1);
            MFMA_STEP(b0, ks);
            if (ks + 2 < 16) LOAD_B(b0, ks + 2);
            MFMA_STEP(b1, ks + 1);
        }

        #pragma unroll
        for (int mb = 0; mb < 4; ++mb) {
            #pragma unroll
            for (int uq = 0; uq < 2; ++uq) {
                const int u = w * 32 + uq * 16 + lc;
                #pragma unroll
                for (int j = 0; j < 4; ++j) {
                    const int gr = row0 + mb * 16 + lr * 4 + j;
                    if (gr < nk) {
                        const int pos = posr[mb * 16 + lr * 4 + j];
                        float cp = 0.0f;
                        if (kk > 0)           cp = c_buf[(size_t)(pos - B_DIM) * H_DIM + u];
                        else if (!done[pos])  cp = c0[(size_t)(pos & (B_DIM - 1)) * H_DIM + u];
                        const float si = sigm(acc[0][mb][uq][j] + bI[uq]);
                        const float sf = sigm(acc[1][mb][uq][j] + bF[uq]);
                        const float tg = tanh_fast(acc[2][mb][uq][j] + bG[uq]);
                        const float so = sigm(acc[3][mb][uq][j] + bO[uq]);
                        const float cn = sf * cp + si * tg;
                        const float hn = so * tanh_fast(cn);
                        c_buf[(size_t)pos * H_DIM + u] = cn;
                        out[(size_t)pos * H_DIM + u]  = hn;
                    }
                }
            }
        }
        __syncthreads();
    }
#undef LOAD_B
#undef MFMA_STEP
}

// Per-segment sequential finisher for steps >= CHAIN_K (independent chains).
__global__ __launch_bounds__(1024) void k_finish(
    const float* __restrict__ x, const unsigned long long* __restrict__ Wq,
    const float* __restrict__ bias,
    const int* __restrict__ counts, const int* __restrict__ offs,
    const int* __restrict__ rowlist, const int* __restrict__ kmap,
    float* __restrict__ out, float* __restrict__ c_buf)
{
    __shared__ float abuf[K_DIM];    // [0,256)=x_t, [256,512)=h_{t-1}
    __shared__ float dots[G_DIM];
    const int g = threadIdx.x;
    const int nch = counts[CHAIN_K];

    for (int m = blockIdx.x; m < nch; m += gridDim.x) {
        const int pos0 = rowlist[offs[CHAIN_K] + m];   // kmap[pos0] == CHAIN_K, t >= 8
        float c_u = 0.0f;
        if (g < H_DIM) {
            abuf[H_DIM + g] = out[(size_t)(pos0 - B_DIM) * H_DIM + g];   // h at t-1
            c_u = c_buf[(size_t)(pos0 - B_DIM) * H_DIM + g];
        }
        int pos = pos0, step = CHAIN_K;
        while (true) {
            if (g < H_DIM) abuf[g] = x[(size_t)pos * D_DIM + g];
            __syncthreads();
            float dot = bias[g];
            #pragma unroll 8
            for (int kq = 0; kq < K_DIM / 4; ++kq) {
                const unsigned long long wq = Wq[(size_t)kq * G_DIM + g];
                const float4 a = *(const float4*)&abuf[kq * 4];
                const unsigned int wlo = (unsigned int)wq;
                const unsigned int whi = (unsigned int)(wq >> 32);
                const float w0 = __uint_as_float(wlo << 16);
                const float w1 = __uint_as_float(wlo & 0xFFFF0000u);
                const float w2 = __uint_as_float(whi << 16);
                const float w3 = __uint_as_float(whi & 0xFFFF0000u);
                dot = fmaf(a.x, w0, dot);
                dot = fmaf(a.y, w1, dot);
                dot = fmaf(a.z, w2, dot);
                dot = fmaf(a.w, w3, dot);
            }
            dots[g] = dot;
            __syncthreads();
            if (g < H_DIM) {
                const float si = sigm(dots[g]);
                const float sf = sigm(dots[H_DIM + g]);
                const float tg = tanh_fast(dots[2 * H_DIM + g]);
                const float so = sigm(dots[3 * H_DIM + g]);
                c_u = sf * c_u + si * tg;
                const float hn = so * tanh_fast(c_u);
                out[(size_t)pos * H_DIM + g]   = hn;
                c_buf[(size_t)pos * H_DIM + g] = c_u;
                abuf[H_DIM + g] = hn;            // h for next step
            }
            pos += B_DIM;
            ++step;
            __syncthreads();                      // h visible; abuf safe to overwrite
            if (pos >= T_DIM * B_DIM) break;
            if (kmap[pos] != step) break;         // segment ended (reset)
        }
        __syncthreads();                          // abuf reuse across chains
    }
}

// hT = out rows at t=511 ; cT = c_buf at t=511
__global__ __launch_bounds__(256) void k_final(const float* __restrict__ c_buf, float* __restrict__ out)
{
    const size_t i = (size_t)blockIdx.x * 256 + threadIdx.x;
    const size_t featN = (size_t)T_DIM * B_DIM * H_DIM;
    const size_t last  = (size_t)(T_DIM - 1) * B_DIM * H_DIM;
    out[featN + i] = out[last + i];
    out[featN + (size_t)B_DIM * H_DIM + i] = c_buf[last + i];
}

__global__ __launch_bounds__(64) void k_zero(int* __restrict__ counts)
{
    if (threadIdx.x < NROUNDS) counts[threadIdx.x] = 0;
}

extern "C" void kernel_launch(void* const* d_in, const int* in_sizes, int n_in,
                              void* d_out, int out_size, void* d_ws, size_t ws_size,
                              hipStream_t stream)
{
    const float* x    = (const float*)d_in[0];
    const float* h0   = (const float*)d_in[1];
    const float* c0   = (const float*)d_in[2];
    const float* W_ih = (const float*)d_in[3];
    const float* W_hh = (const float*)d_in[4];
    const float* b_ih = (const float*)d_in[5];
    const float* b_hh = (const float*)d_in[6];
    const int*   done = (const int*)d_in[7];
    float* out = (float*)d_out;

    char* ws = (char*)d_ws;
    size_t off = 0;
    float* c_buf = (float*)(ws + off);            off += (size_t)T_DIM * B_DIM * H_DIM * 4;  // 128 MiB
    unsigned int* Wb = (unsigned int*)(ws + off); off += (size_t)(K_DIM / 2) * G_DIM * 4;    // 1 MiB
    unsigned long long* Wq = (unsigned long long*)(ws + off); off += (size_t)(K_DIM / 4) * G_DIM * 8; // 1 MiB
    float* bias = (float*)(ws + off);             off += (size_t)G_DIM * 4;
    int* kmap    = (int*)(ws + off);              off += (size_t)T_DIM * B_DIM * 4;
    int* rowlist = (int*)(ws + off);              off += (size_t)T_DIM * B_DIM * 4;
    int* counts  = (int*)(ws + off);              off += 256;
    int* offs    = (int*)(ws + off);              off += 256;
    int* cursor  = (int*)(ws + off);              off += 256;

    k_zero<<<1, 64, 0, stream>>>(counts);
    k_prep_weights<<<1024, 256, 0, stream>>>(W_ih, W_hh, b_ih, b_hh, Wb, bias);
    k_prep_wq<<<512, 256, 0, stream>>>(W_ih, W_hh, Wq);
    k_kmap<<<T_DIM, 256, 0, stream>>>(done, kmap, counts);
    k_offs<<<1, 64, 0, stream>>>(counts, offs, cursor);
    k_scatter<<<T_DIM * B_DIM / 256, 256, 0, stream>>>(kmap, offs, cursor, rowlist);

    int est = 70000;   // statistical upper bound on round-0 rows; ~halves each round
    for (int k = 0; k < CHAIN_K; ++k) {
        int grid = est / TILE_ROWS + 8;
        if (grid > 2048) grid = 2048;
        if (grid < 8) grid = 8;
        k_round<<<grid, 512, 0, stream>>>(x, h0, c0, done, (const short*)Wb, bias,
                                          counts, offs, rowlist, out, c_buf, k);
        est >>= 1;
    }
    // ~counts[8] (~256) independent chains; 512 blocks grid-stride (extras exit fast)
    k_finish<<<512, 1024, 0, stream>>>(x, Wq, bias, counts, offs, rowlist, kmap, out, c_buf);
    k_final<<<B_DIM * H_DIM / 256, 256, 0, stream>>>(c_buf, out);
}